// Round 7
// baseline (319.761 us; speedup 1.0000x reference)
//
#include <hip/hip_runtime.h>
#include <stdint.h>

using bf16 = __bf16;
typedef __bf16 bf16x8 __attribute__((ext_vector_type(8)));
typedef __bf16 bf16x4 __attribute__((ext_vector_type(4)));
typedef float f32x4 __attribute__((ext_vector_type(4)));

#define H_ 16
#define KV_ 4
#define D_ 128
#define WIN_ 1024
#define B_ 2
#define S_ 2048
#define E_ 2048
#define HD_ 2048

// async global->LDS, 16B per lane. LDS dest must be wave-uniform base + lane*16.
__device__ __forceinline__ void gld_lds16(const void* gptr, void* lptr) {
    __builtin_amdgcn_global_load_lds(
        (__attribute__((address_space(1))) void*)(uintptr_t)gptr,
        (__attribute__((address_space(3))) void*)(uintptr_t)lptr, 16, 0, 0);
}

// ---------------- fused fp32 -> bf16 conversion (x, Wq, Wk, Wv, Wo -> one contiguous dst) ----
__global__ __launch_bounds__(256) void cvt_all(const float* __restrict__ x,
                                               const float* __restrict__ wq,
                                               const float* __restrict__ wk,
                                               const float* __restrict__ wv,
                                               const float* __restrict__ wo,
                                               bf16* __restrict__ dst) {
    int i = (blockIdx.x * 256 + threadIdx.x) * 4;  // into 18,874,368-elem concatenation
    const float* src;
    int off;
    if (i < 8388608)       { src = x;  off = 0; }
    else if (i < 12582912) { src = wq; off = 8388608; }
    else if (i < 13631488) { src = wk; off = 12582912; }
    else if (i < 14680064) { src = wv; off = 13631488; }
    else                   { src = wo; off = 14680064; }
    const float4 v = *(const float4*)(src + (i - off));
    bf16x4 o = {(bf16)v.x, (bf16)v.y, (bf16)v.z, (bf16)v.w};
    *(bf16x4*)(dst + i) = o;
}

// BK=64 swizzle scheme: LDS row = 64 bf16 = 128 B (full bank wrap), 8 x 16B units/row.
// Physical unit p of row r holds logical unit p ^ (r&7).

// ---------------- GEMM: C[m,n] = sum_k A[m,k] * W[n,k] (plain epilogue; out-proj) ----------
template <typename OutT>
__global__ __launch_bounds__(256) void gemm_bt(const bf16* __restrict__ A,
                                               const bf16* __restrict__ W,
                                               OutT* __restrict__ C, int K, int ldc) {
    __shared__ alignas(16) bf16 As[128 * 64];
    __shared__ alignas(16) bf16 Bs[128 * 64];
    const int t = threadIdx.x;
    const int lane = t & 63;
    const int wave = t >> 6;
    const int l15 = lane & 15;
    const int quad = lane >> 4;
    const int fsw = l15 & 7;  // fragment-read swizzle
    const int wm = (wave & 1) * 64;
    const int wn = (wave >> 1) * 64;
    const int m0 = blockIdx.x * 128;
    const int n0 = blockIdx.y * 128;

    f32x4 acc[4][4] = {};

    const int sr = t >> 3;                              // 0..31
    const int su = ((t & 7) ^ ((t >> 3) & 7)) * 8;      // swizzled source unit
    const bf16* Ap = A + (size_t)(m0 + sr) * K + su;
    const bf16* Wp = W + (size_t)(n0 + sr) * K + su;

    for (int k0 = 0; k0 < K; k0 += 64) {
#pragma unroll
        for (int c = 0; c < 4; ++c) {
            gld_lds16(Ap + k0 + (size_t)c * 32 * K, &As[c * 2048 + t * 8]);
            gld_lds16(Wp + k0 + (size_t)c * 32 * K, &Bs[c * 2048 + t * 8]);
        }
        __syncthreads();
#pragma unroll
        for (int kh = 0; kh < 2; ++kh) {
            bf16x8 af[4], bfr[4];
#pragma unroll
            for (int i = 0; i < 4; ++i) {
                af[i] = *(const bf16x8*)&As[(wm + i * 16 + l15) * 64 +
                                            (((kh * 4 + quad) ^ fsw) * 8)];
                bfr[i] = *(const bf16x8*)&Bs[(wn + i * 16 + l15) * 64 +
                                             (((kh * 4 + quad) ^ fsw) * 8)];
            }
#pragma unroll
            for (int i = 0; i < 4; ++i)
#pragma unroll
                for (int j = 0; j < 4; ++j)
                    acc[i][j] =
                        __builtin_amdgcn_mfma_f32_16x16x32_bf16(af[i], bfr[j], acc[i][j], 0, 0, 0);
        }
        __syncthreads();
    }
#pragma unroll
    for (int i = 0; i < 4; ++i) {
        const int row = m0 + wm + i * 16 + quad * 4;
#pragma unroll
        for (int j = 0; j < 4; ++j) {
            const int col = n0 + wn + j * 16 + l15;
#pragma unroll
            for (int r = 0; r < 4; ++r) C[(size_t)(row + r) * ldc + col] = (OutT)acc[i][j][r];
        }
    }
}

// ---------------- QKV GEMM with fused RoPE + RMSNorm + V-transpose epilogue ----------------
__global__ __launch_bounds__(256) void gemm_qkv_rope(const bf16* __restrict__ A,
                                                     const bf16* __restrict__ W,
                                                     const float* __restrict__ cosp,
                                                     const float* __restrict__ sinp,
                                                     bf16* __restrict__ qn,
                                                     bf16* __restrict__ kn,
                                                     bf16* __restrict__ vt) {
    __shared__ alignas(16) unsigned char smem[128 * 136 * 2];  // 34,816 B union
    bf16* As = (bf16*)smem;                  // 128*64 = 16 KB  (K-loop)
    bf16* Bs = (bf16*)(smem + 16384);        // 128*64 = 16 KB  (K-loop)
    bf16* Cs = (bf16*)smem;                  // 128*136 = 34 KB (epilogue, aliases As/Bs)
    const int t = threadIdx.x;
    const int lane = t & 63;
    const int wave = t >> 6;
    const int l15 = lane & 15;
    const int quad = lane >> 4;
    const int fsw = l15 & 7;
    const int wm = (wave & 1) * 64;
    const int wn = (wave >> 1) * 64;
    const int m0 = blockIdx.x * 128;
    const int n0 = blockIdx.y * 128;
    const int K = E_;

    f32x4 acc[4][4] = {};

    const int sr = t >> 3;
    const int su = ((t & 7) ^ ((t >> 3) & 7)) * 8;
    const bf16* Ap = A + (size_t)(m0 + sr) * K + su;
    const bf16* Wp = W + (size_t)(n0 + sr) * K + su;

    for (int k0 = 0; k0 < K; k0 += 64) {
#pragma unroll
        for (int c = 0; c < 4; ++c) {
            gld_lds16(Ap + k0 + (size_t)c * 32 * K, &As[c * 2048 + t * 8]);
            gld_lds16(Wp + k0 + (size_t)c * 32 * K, &Bs[c * 2048 + t * 8]);
        }
        __syncthreads();
#pragma unroll
        for (int kh = 0; kh < 2; ++kh) {
            bf16x8 af[4], bfr[4];
#pragma unroll
            for (int i = 0; i < 4; ++i) {
                af[i] = *(const bf16x8*)&As[(wm + i * 16 + l15) * 64 +
                                            (((kh * 4 + quad) ^ fsw) * 8)];
                bfr[i] = *(const bf16x8*)&Bs[(wn + i * 16 + l15) * 64 +
                                             (((kh * 4 + quad) ^ fsw) * 8)];
            }
#pragma unroll
            for (int i = 0; i < 4; ++i)
#pragma unroll
                for (int j = 0; j < 4; ++j)
                    acc[i][j] =
                        __builtin_amdgcn_mfma_f32_16x16x32_bf16(af[i], bfr[j], acc[i][j], 0, 0, 0);
        }
        __syncthreads();
    }

#pragma unroll
    for (int i = 0; i < 4; ++i) {
        const int row = wm + i * 16 + quad * 4;
#pragma unroll
        for (int j = 0; j < 4; ++j) {
            const int col = wn + j * 16 + l15;
#pragma unroll
            for (int r = 0; r < 4; ++r) Cs[(row + r) * 136 + col] = (bf16)acc[i][j][r];
        }
    }
    __syncthreads();

    const int unit = n0 >> 7;  // == blockIdx.y
    if (unit < 20) {
        const int row = t >> 1;
        const int half = t & 1;
        const int gr = m0 + row;
        const int bb = gr >> 11;
        const int s = gr & 2047;
        const bf16* crow = &Cs[row * 136 + half * 32];
        const float* cp = cosp + s * 64 + half * 32;
        const float* sp = sinp + s * 64 + half * 32;
        bf16x8 xa[4], xb2[4];
#pragma unroll
        for (int u = 0; u < 4; ++u) {
            xa[u] = *(const bf16x8*)(crow + u * 8);
            xb2[u] = *(const bf16x8*)(crow + 64 + u * 8);
        }
        float y1[32], y2[32], ss = 0.0f;
#pragma unroll
        for (int u = 0; u < 4; ++u)
#pragma unroll
            for (int e = 0; e < 8; ++e) {
                const int jj = u * 8 + e;
                const float x1 = (float)xa[u][e];
                const float x2 = (float)xb2[u][e];
                const float c = cp[jj];
                const float sn = sp[jj];
                y1[jj] = x1 * c + x2 * sn;
                y2[jj] = x2 * c - x1 * sn;
                ss += y1[jj] * y1[jj] + y2[jj] * y2[jj];
            }
        ss += __shfl_xor(ss, 1, 64);
        float rr = rsqrtf(ss * (1.0f / 128.0f) + 1.1920929e-7f);
        bf16* dst;
        if (unit < 16) {
            rr *= 0.12751740f;  // D^-0.5 * log2(e): exp2-domain softmax in attn
            dst = qn + ((size_t)(bb * H_ + unit) * S_ + s) * 128 + half * 32;
        } else {
            dst = kn + ((size_t)(bb * KV_ + (unit - 16)) * S_ + s) * 128 + half * 32;
        }
#pragma unroll
        for (int u = 0; u < 4; ++u) {
            bf16x8 p1, p2;
#pragma unroll
            for (int e = 0; e < 8; ++e) {
                p1[e] = (bf16)(y1[u * 8 + e] * rr);
                p2[e] = (bf16)(y2[u * 8 + e] * rr);
            }
            *(bf16x8*)(dst + u * 8) = p1;
            *(bf16x8*)(dst + 64 + u * 8) = p2;
        }
    } else {
        const int jv = unit - 20;
        const int d = t >> 1;
        const int sl0 = (t & 1) * 64;
        const int s0 = (m0 & 2047) + sl0;
        const int bb = m0 >> 11;
        bf16* vdst = vt + ((size_t)(bb * KV_ + jv) * 128 + d) * S_ + s0;
#pragma unroll
        for (int u = 0; u < 8; ++u) {
            bf16x8 pk;
#pragma unroll
            for (int e = 0; e < 8; ++e) pk[e] = Cs[(sl0 + u * 8 + e) * 136 + d];
            *(bf16x8*)(vdst + u * 8) = pk;
        }
    }
}

// ---------------- flash attention: 2 waves x 32 q, shared kf/vf reads ----------------
// Block = 128 threads = 2 waves; wave handles q [qw0, qw0+32) as two 16-row groups (A,B)
// that share every Ks/Vs b128 read (halves LDS traffic vs 16q/wave).
__global__ __launch_bounds__(128) void attn_fwd(const bf16* __restrict__ Qn,
                                                const bf16* __restrict__ Kn,
                                                const bf16* __restrict__ Vt,
                                                bf16* __restrict__ Out) {
    __shared__ alignas(16) bf16 Ks[64 * 128];   // 16 KB, row=key, swizzled units
    __shared__ alignas(16) bf16 Vs[128 * 64];   // 16 KB, row=d, swizzled units
    __shared__ alignas(16) bf16 Ps[2 * 16 * 64]; // 4 KB, per-wave 16x64, reused per group

    const int t = threadIdx.x;
    const int lane = t & 63;
    const int wave = t >> 6;
    const int l15 = lane & 15;
    const int quad = lane >> 4;
    const int swz = l15 & 7;
    const int qb0 = blockIdx.x * 64;
    const int h = blockIdx.y;
    const int b = blockIdx.z;
    const int hk = h >> 2;
    const int qw0 = qb0 + wave * 32;

    // Q fragments (B-operand) for both row groups
    const bf16* qbaseA = Qn + ((size_t)((b * H_ + h) * S_) + qw0 + l15) * 128;
    const bf16* qbaseB = qbaseA + 16 * 128;
    bf16x8 qfA[4], qfB[4];
#pragma unroll
    for (int c4 = 0; c4 < 4; ++c4) {
        qfA[c4] = *(const bf16x8*)(qbaseA + c4 * 32 + quad * 8);
        qfB[c4] = *(const bf16x8*)(qbaseB + c4 * 32 + quad * 8);
    }

    f32x4 oA[8] = {}, oB[8] = {};
    float mA = -1e30f, lA = 0.0f, mB = -1e30f, lB = 0.0f;

    const bf16* kroot = Kn + (size_t)((b * KV_ + hk) * S_) * 128;
    const bf16* vroot = Vt + (size_t)((b * KV_ + hk) * 128) * S_;

    // staging (128 threads, 8 calls each for Ks and Vs)
    const bf16* kst = kroot + (size_t)(t >> 4) * 128 + ((t & 15) ^ (t >> 4)) * 8;
    const bf16* vst = vroot + (size_t)(t >> 3) * S_ + ((t & 7) ^ ((t >> 3) & 7)) * 8;
    bf16* ksl = &Ks[t * 8];
    bf16* vsl = &Vs[t * 8];

    int lo = qb0 - (WIN_ - 1);
    if (lo < 0) lo = 0;
    const int kb_start = lo & ~63;
    const int kb_end = qb0 + 64;

    bf16* pw = &Ps[wave * 1024 + l15 * 64];

    for (int kb = kb_start; kb < kb_end; kb += 64) {
#pragma unroll
        for (int c = 0; c < 8; ++c) gld_lds16(kst + (size_t)(kb + c * 8) * 128, ksl + c * 1024);
#pragma unroll
        for (int c = 0; c < 8; ++c)
            gld_lds16(vst + (size_t)(c * 16) * S_ + kb, vsl + c * 1024);
        __syncthreads();

        const bool wave_active = (kb + 63 >= qw0 - (WIN_ - 1));
        if (wave_active) {
            // joint S^T = K * Q^T for both groups, kf read once
            f32x4 sA[4] = {}, sB[4] = {};
#pragma unroll
            for (int kblk = 0; kblk < 4; ++kblk)
#pragma unroll
                for (int c4 = 0; c4 < 4; ++c4) {
                    bf16x8 kf = *(const bf16x8*)&Ks[(kblk * 16 + l15) * 128 +
                                                    (((c4 * 4 + quad) ^ swz) * 8)];
                    sA[kblk] = __builtin_amdgcn_mfma_f32_16x16x32_bf16(kf, qfA[c4], sA[kblk], 0, 0, 0);
                    sB[kblk] = __builtin_amdgcn_mfma_f32_16x16x32_bf16(kf, qfB[c4], sB[kblk], 0, 0, 0);
                }

            bf16x8 pfA[2], pfB[2];

            // ---- group A softmax + P round-trip ----
            {
                const int qg0 = qw0;
                const int qq = qg0 + l15;
                float sv[16];
                const bool interior = (kb + 63 <= qg0) && (kb >= qg0 + 15 - (WIN_ - 1));
                if (interior) {
#pragma unroll
                    for (int kblk = 0; kblk < 4; ++kblk)
#pragma unroll
                        for (int r = 0; r < 4; ++r) sv[kblk * 4 + r] = sA[kblk][r];
                } else {
#pragma unroll
                    for (int kblk = 0; kblk < 4; ++kblk)
#pragma unroll
                        for (int r = 0; r < 4; ++r) {
                            const int key = kb + kblk * 16 + quad * 4 + r;
                            const bool valid = (key <= qq) && (qq - key < WIN_);
                            sv[kblk * 4 + r] = valid ? sA[kblk][r] : -1e30f;
                        }
                }
                float mc = sv[0];
#pragma unroll
                for (int i = 1; i < 16; ++i) mc = fmaxf(mc, sv[i]);
                mc = fmaxf(mc, __shfl_xor(mc, 16, 64));
                mc = fmaxf(mc, __shfl_xor(mc, 32, 64));
                const float mnew = fmaxf(mA, mc);
                const float al = __builtin_amdgcn_exp2f(mA - mnew);
                float ls = 0.0f;
#pragma unroll
                for (int i = 0; i < 16; ++i) {
                    sv[i] = __builtin_amdgcn_exp2f(sv[i] - mnew);
                    ls += sv[i];
                }
                ls += __shfl_xor(ls, 16, 64);
                ls += __shfl_xor(ls, 32, 64);
                lA = lA * al + ls;
                mA = mnew;
#pragma unroll
                for (int d = 0; d < 8; ++d) oA[d] *= al;
#pragma unroll
                for (int kblk = 0; kblk < 4; ++kblk) {
                    bf16x4 pb = {(bf16)sv[kblk * 4 + 0], (bf16)sv[kblk * 4 + 1],
                                 (bf16)sv[kblk * 4 + 2], (bf16)sv[kblk * 4 + 3]};
                    const int phys = (kblk * 2 + (quad >> 1)) ^ swz;
                    *(bf16x4*)&pw[phys * 8 + (quad & 1) * 4] = pb;
                }
                asm volatile("s_waitcnt lgkmcnt(0)" ::: "memory");
                pfA[0] = *(const bf16x8*)&pw[((quad) ^ swz) * 8];
                pfA[1] = *(const bf16x8*)&pw[((4 + quad) ^ swz) * 8];
                asm volatile("s_waitcnt lgkmcnt(0)" ::: "memory");
            }
            // ---- group B softmax + P round-trip (reuses same Ps region) ----
            {
                const int qg0 = qw0 + 16;
                const int qq = qg0 + l15;
                float sv[16];
                const bool interior = (kb + 63 <= qg0) && (kb >= qg0 + 15 - (WIN_ - 1));
                if (interior) {
#pragma unroll
                    for (int kblk = 0; kblk < 4; ++kblk)
#pragma unroll
                        for (int r = 0; r < 4; ++r) sv[kblk * 4 + r] = sB[kblk][r];
                } else {
#pragma unroll
                    for (int kblk = 0; kblk < 4; ++kblk)
#pragma unroll
                        for (int r = 0; r < 4; ++r) {
                            const int key = kb + kblk * 16 + quad * 4 + r;
                            const bool valid = (key <= qq) && (qq - key < WIN_);
                            sv[kblk * 4 + r] = valid ? sB[kblk][r] : -1e30f;
                        }
                }
                float mc = sv[0];
#pragma unroll
                for (int i = 1; i < 16; ++i) mc = fmaxf(mc, sv[i]);
                mc = fmaxf(mc, __shfl_xor(mc, 16, 64));
                mc = fmaxf(mc, __shfl_xor(mc, 32, 64));
                const float mnew = fmaxf(mB, mc);
                const float al = __builtin_amdgcn_exp2f(mB - mnew);
                float ls = 0.0f;
#pragma unroll
                for (int i = 0; i < 16; ++i) {
                    sv[i] = __builtin_amdgcn_exp2f(sv[i] - mnew);
                    ls += sv[i];
                }
                ls += __shfl_xor(ls, 16, 64);
                ls += __shfl_xor(ls, 32, 64);
                lB = lB * al + ls;
                mB = mnew;
#pragma unroll
                for (int d = 0; d < 8; ++d) oB[d] *= al;
#pragma unroll
                for (int kblk = 0; kblk < 4; ++kblk) {
                    bf16x4 pb = {(bf16)sv[kblk * 4 + 0], (bf16)sv[kblk * 4 + 1],
                                 (bf16)sv[kblk * 4 + 2], (bf16)sv[kblk * 4 + 3]};
                    const int phys = (kblk * 2 + (quad >> 1)) ^ swz;
                    *(bf16x4*)&pw[phys * 8 + (quad & 1) * 4] = pb;
                }
                asm volatile("s_waitcnt lgkmcnt(0)" ::: "memory");
                pfB[0] = *(const bf16x8*)&pw[((quad) ^ swz) * 8];
                pfB[1] = *(const bf16x8*)&pw[((4 + quad) ^ swz) * 8];
            }
            // ---- joint PV: vf read once serves both groups ----
#pragma unroll
            for (int kc = 0; kc < 2; ++kc) {
                const int up = ((kc * 4 + quad) ^ swz) * 8;
#pragma unroll
                for (int dblk = 0; dblk < 8; ++dblk) {
                    bf16x8 vf = *(const bf16x8*)&Vs[(dblk * 16 + l15) * 64 + up];
                    oA[dblk] = __builtin_amdgcn_mfma_f32_16x16x32_bf16(vf, pfA[kc], oA[dblk], 0, 0, 0);
                    oB[dblk] = __builtin_amdgcn_mfma_f32_16x16x32_bf16(vf, pfB[kc], oB[dblk], 0, 0, 0);
                }
            }
        }
        __syncthreads();
    }

    // normalize + write both groups
    {
        const float inv = 1.0f / lA;
        bf16* ob = Out + (size_t)(b * S_ + qw0 + l15) * HD_ + h * 128;
#pragma unroll
        for (int dblk = 0; dblk < 8; ++dblk) {
            bf16x4 ov = {(bf16)(oA[dblk][0] * inv), (bf16)(oA[dblk][1] * inv),
                         (bf16)(oA[dblk][2] * inv), (bf16)(oA[dblk][3] * inv)};
            *(bf16x4*)&ob[dblk * 16 + quad * 4] = ov;
        }
    }
    {
        const float inv = 1.0f / lB;
        bf16* ob = Out + (size_t)(b * S_ + qw0 + 16 + l15) * HD_ + h * 128;
#pragma unroll
        for (int dblk = 0; dblk < 8; ++dblk) {
            bf16x4 ov = {(bf16)(oB[dblk][0] * inv), (bf16)(oB[dblk][1] * inv),
                         (bf16)(oB[dblk][2] * inv), (bf16)(oB[dblk][3] * inv)};
            *(bf16x4*)&ob[dblk * 16 + quad * 4] = ov;
        }
    }
}

// ---------------- launch ----------------
extern "C" void kernel_launch(void* const* d_in, const int* in_sizes, int n_in, void* d_out,
                              int out_size, void* d_ws, size_t ws_size, hipStream_t stream) {
    const float* x = (const float*)d_in[0];
    const float* cosp = (const float*)d_in[1];
    const float* sinp = (const float*)d_in[2];
    const float* Wq = (const float*)d_in[3];
    const float* Wk = (const float*)d_in[4];
    const float* Wv = (const float*)d_in[5];
    const float* Wo = (const float*)d_in[6];
    float* out = (float*)d_out;

    constexpr size_t MB = 1ull << 20;
    char* ws = (char*)d_ws;
    bf16* xb    = (bf16*)(ws + 0);          // x bf16 (4096x2048)        16 MB
    bf16* wqkv  = (bf16*)(ws + 16 * MB);    // Wq|Wk|Wv bf16 (3072x2048) 12 MB
    bf16* wo    = (bf16*)(ws + 28 * MB);    // Wo bf16 (2048x2048)        8 MB
    bf16* qn    = (bf16*)(ws + 40 * MB);    // (B,H,S,D)                 16 MB
    bf16* kn    = (bf16*)(ws + 56 * MB);    // (B,KV,S,D)                 4 MB
    bf16* vt    = (bf16*)(ws + 60 * MB);    // (B,KV,D,S)                 4 MB
    bf16* attnb = (bf16*)(ws + 64 * MB);    // (B,S,H*D)                 16 MB

    cvt_all<<<18432, 256, 0, stream>>>(x, Wq, Wk, Wv, Wo, xb);
    gemm_qkv_rope<<<dim3(32, 24), 256, 0, stream>>>(xb, wqkv, cosp, sinp, qn, kn, vt);
    attn_fwd<<<dim3(32, 16, 2), 128, 0, stream>>>(qn, kn, vt, attnb);
    gemm_bt<float><<<dim3(32, 16), 256, 0, stream>>>(attnb, wo, out, 2048, 2048);
}